// Round 1
// baseline (521.527 us; speedup 1.0000x reference)
//
#include <hip/hip_runtime.h>

#define NB 32
#define NGT 100
#define NL 8400
#define NC 80
#define KTOP 13

__device__ __forceinline__ float clamp0(float x) { return fmaxf(x, 0.f); }

// ---------------- Kernel A: per-(b,n) metric + stable top-13 ----------------
__global__ __launch_bounds__(256) void topk_kernel(
    const float* __restrict__ ps, const float* __restrict__ pb,
    const float* __restrict__ ap, const int* __restrict__ gl,
    const float* __restrict__ gtb, int* __restrict__ topk_out)
{
  __shared__ float met[NL];
  __shared__ unsigned long long red[256];
  const int bn = blockIdx.x;
  const int b = bn / NGT;
  const float gx1 = gtb[bn * 4 + 0], gy1 = gtb[bn * 4 + 1];
  const float gx2 = gtb[bn * 4 + 2], gy2 = gtb[bn * 4 + 3];
  const int cls = gl[bn];
  const float ga = clamp0(gx2 - gx1) * clamp0(gy2 - gy1);
  const float4* pbb = (const float4*)pb + (size_t)b * NL;
  const float* psb = ps + (size_t)b * NL * NC;
  const float2* apb = (const float2*)ap;

  for (int l = threadIdx.x; l < NL; l += 256) {
    float4 p = pbb[l];
    float ox = fminf(p.z, gx2) - fmaxf(p.x, gx1);
    float oy = fminf(p.w, gy2) - fmaxf(p.y, gy1);
    float ov = clamp0(ox) * clamp0(oy);
    float pa = clamp0(p.z - p.x) * clamp0(p.w - p.y);
    float iou = ov / (ga + pa - ov + 1e-9f);
    float2 a = apb[l];
    float ins = (fminf(fminf(a.x - gx1, a.y - gy1),
                       fminf(gx2 - a.x, gy2 - a.y)) > 1e-9f) ? 1.f : 0.f;
    float sc = psb[(size_t)l * NC + cls];
    float i2 = iou * iou;
    met[l] = sc * i2 * i2 * i2 * ins;
  }
  __syncthreads();

  // 13 rounds of argmax (value desc, index asc) == jax.lax.top_k tie semantics
  for (int k = 0; k < KTOP; ++k) {
    unsigned long long best = 0ull;
    for (int l = threadIdx.x; l < NL; l += 256) {
      float v = met[l];
      if (v >= 0.f) {  // marked entries are -1.f
        unsigned long long key =
            ((unsigned long long)__float_as_uint(v) << 32) |
            (unsigned long long)(0xFFFFFFFFu - (unsigned)l);
        if (key > best) best = key;
      }
    }
    red[threadIdx.x] = best;
    __syncthreads();
    for (int s = 128; s > 0; s >>= 1) {
      if (threadIdx.x < s) {
        unsigned long long o = red[threadIdx.x + s];
        if (o > red[threadIdx.x]) red[threadIdx.x] = o;
      }
      __syncthreads();
    }
    int idx = (int)(0xFFFFFFFFu - (unsigned)(red[0] & 0xFFFFFFFFull));
    if (threadIdx.x == 0) {
      topk_out[bn * KTOP + k] = idx;
      met[idx] = -1.f;
    }
    __syncthreads();
  }
}

// ------------- Kernel B: per-(b,l) assignment (n*, align*, iou*) -------------
__global__ __launch_bounds__(256) void assign_kernel(
    const float* __restrict__ ps, const float* __restrict__ pb,
    const float* __restrict__ ap, const int* __restrict__ gl,
    const float* __restrict__ gtb, const float* __restrict__ pad,
    const int* __restrict__ topk, int* __restrict__ nstar,
    float* __restrict__ astar, unsigned* __restrict__ maxm,
    unsigned* __restrict__ maxi)
{
  __shared__ float4 sgt[NGT];
  __shared__ int sgl[NGT];
  __shared__ float spad[NGT];
  __shared__ int stopk[NGT * KTOP];
  const int b = blockIdx.y;
  for (int i = threadIdx.x; i < NGT; i += 256) {
    sgt[i] = ((const float4*)gtb)[b * NGT + i];
    sgl[i] = gl[b * NGT + i];
    spad[i] = pad[b * NGT + i];
  }
  for (int i = threadIdx.x; i < NGT * KTOP; i += 256)
    stopk[i] = topk[b * NGT * KTOP + i];
  __syncthreads();

  const int l = blockIdx.x * 256 + threadIdx.x;
  if (l >= NL) return;

  float4 p = ((const float4*)pb)[(size_t)b * NL + l];
  float2 a = ((const float2*)ap)[l];
  float pa = clamp0(p.z - p.x) * clamp0(p.w - p.y);

  int mps = 0, n_single = -1, max_n = 0;
  float iou_single = 0.f, max_iou = -1.f;
  for (int n = 0; n < NGT; ++n) {
    float4 g = sgt[n];
    float ox = fminf(p.z, g.z) - fmaxf(p.x, g.x);
    float oy = fminf(p.w, g.w) - fmaxf(p.y, g.y);
    float ov = clamp0(ox) * clamp0(oy);
    float ga = clamp0(g.z - g.x) * clamp0(g.w - g.y);
    float iou = ov / (ga + pa - ov + 1e-9f);
    if (iou > max_iou) { max_iou = iou; max_n = n; }  // argmax over ALL n (incl. pad)
    bool ins = fminf(fminf(a.x - g.x, a.y - g.y),
                     fminf(g.z - a.x, g.w - a.y)) > 1e-9f;
    if (ins && spad[n] != 0.f) {
      bool hit = false;
#pragma unroll
      for (int k = 0; k < KTOP; ++k) hit |= (stopk[n * KTOP + k] == l);
      if (hit) { mps++; n_single = n; iou_single = iou; }
    }
  }

  int ns; float iou_s;
  if (mps == 0)      { ns = -1;       iou_s = 0.f; }
  else if (mps == 1) { ns = n_single; iou_s = iou_single; }
  else               { ns = max_n;    iou_s = max_iou; }  // is_max_iou replacement

  float al_s = 0.f;
  if (ns >= 0) {
    float sc = ps[((size_t)b * NL + l) * NC + sgl[ns]];
    float i2 = iou_s * iou_s;
    al_s = sc * i2 * i2 * i2;
    atomicMax(&maxm[b * NGT + ns], __float_as_uint(al_s));
    atomicMax(&maxi[b * NGT + ns], __float_as_uint(iou_s));
  }
  nstar[b * NL + l] = ns;
  astar[b * NL + l] = al_s;
}

// ---------------- Kernel C: per-(b,l) VFL-BCE + GIoU, reduce ----------------
__global__ __launch_bounds__(256) void loss_kernel(
    const float* __restrict__ ps, const float* __restrict__ pb,
    const float* __restrict__ gtb, const int* __restrict__ gl,
    const int* __restrict__ nstar, const float* __restrict__ astar,
    const unsigned* __restrict__ maxm, const unsigned* __restrict__ maxi,
    double* __restrict__ acc)
{
  const int b = blockIdx.y;
  const int l = blockIdx.x * 256 + threadIdx.x;
  double cs = 0.0, isum = 0.0, as = 0.0;
  if (l < NL) {
    const float* psrow = ps + ((size_t)b * NL + l) * NC;
    int ns = nstar[b * NL + l];
    float scale = 0.f;
    int j = NC;  // "no class"
    if (ns >= 0) {
      float mm = __uint_as_float(maxm[b * NGT + ns]);
      float mi = __uint_as_float(maxi[b * NGT + ns]);
      scale = astar[b * NL + l] / (mm + 1e-9f) * mi;
      j = gl[b * NGT + ns];
      as = (double)scale;
      // GIoU(pred, assigned gt)
      float4 p = ((const float4*)pb)[(size_t)b * NL + l];
      float4 g = ((const float4*)gtb)[b * NGT + ns];
      float x1 = fmaxf(p.x, g.x), y1 = fmaxf(p.y, g.y);
      float x2 = fminf(p.z, g.z), y2 = fminf(p.w, g.w);
      float ov = clamp0(x2 - x1) * clamp0(y2 - y1);
      float pa = clamp0(p.z - p.x) * clamp0(p.w - p.y);
      float ga = clamp0(g.z - g.x) * clamp0(g.w - g.y);
      float un = pa + ga - ov + 1e-10f;
      float iou = ov / un;
      float cx1 = fminf(p.x, g.x), cy1 = fminf(p.y, g.y);
      float cx2 = fmaxf(p.z, g.z), cy2 = fmaxf(p.w, g.w);
      float cc = clamp0(cx2 - cx1) * clamp0(cy2 - cy1) + 1e-10f;
      float gi = 1.f - (iou - (cc - un) / cc);
      isum = (double)(gi * scale);
    }
    float csum = 0.f;
    for (int c = 0; c < NC; ++c) {
      float s = psrow[c];
      float pcl = fminf(fmaxf(s, 1e-9f), 1.f - 1e-9f);
      float lp1 = log1pf(-pcl);
      if (c == j) {
        csum += -(scale * logf(pcl) + (1.f - scale) * lp1) * scale;
      } else {
        csum += -lp1 * 0.75f * s * s;
      }
    }
    cs = (double)csum;
  }
  // wave(64)-level reduction, then one f64 atomic per wave
  for (int off = 32; off > 0; off >>= 1) {
    cs += __shfl_down(cs, off);
    isum += __shfl_down(isum, off);
    as += __shfl_down(as, off);
  }
  if ((threadIdx.x & 63) == 0) {
    atomicAdd(&acc[0], cs);
    atomicAdd(&acc[1], isum);
    atomicAdd(&acc[2], as);
  }
}

__global__ void fin_kernel(const double* __restrict__ acc, float* __restrict__ out) {
  double s = acc[2] > 1.0 ? acc[2] : 1.0;
  out[0] = (float)((acc[0] + 2.5 * acc[1]) / s);
}

// ---------------------------------------------------------------------------
extern "C" void kernel_launch(void* const* d_in, const int* in_sizes, int n_in,
                              void* d_out, int out_size, void* d_ws, size_t ws_size,
                              hipStream_t stream) {
  const float* ps  = (const float*)d_in[0];   // [32,8400,80]
  const float* pbx = (const float*)d_in[1];   // [32,8400,4]
  const float* ap  = (const float*)d_in[2];   // [8400,2]
  const int*   gl  = (const int*)d_in[3];     // [32,100,1]
  const float* gtb = (const float*)d_in[4];   // [32,100,4]
  const float* pad = (const float*)d_in[5];   // [32,100,1]

  char* ws = (char*)d_ws;
  const size_t OFF_ACC   = 0;                               // 3 doubles
  const size_t OFF_MAXM  = 24;                              // 3200 u32
  const size_t OFF_MAXI  = OFF_MAXM + 4ul * NB * NGT;       // 3200 u32
  const size_t OFF_TOPK  = OFF_MAXI + 4ul * NB * NGT;       // 41600 i32
  const size_t OFF_NSTAR = OFF_TOPK + 4ul * NB * NGT * KTOP;// 268800 i32
  const size_t OFF_ASTAR = OFF_NSTAR + 4ul * NB * NL;       // 268800 f32

  double*   acc   = (double*)(ws + OFF_ACC);
  unsigned* maxm  = (unsigned*)(ws + OFF_MAXM);
  unsigned* maxi  = (unsigned*)(ws + OFF_MAXI);
  int*      topk  = (int*)(ws + OFF_TOPK);
  int*      nstar = (int*)(ws + OFF_NSTAR);
  float*    astar = (float*)(ws + OFF_ASTAR);

  hipMemsetAsync(ws, 0, OFF_TOPK, stream);  // zero acc + maxm + maxi

  hipLaunchKernelGGL(topk_kernel, dim3(NB * NGT), dim3(256), 0, stream,
                     ps, pbx, ap, gl, gtb, topk);
  hipLaunchKernelGGL(assign_kernel, dim3((NL + 255) / 256, NB), dim3(256), 0, stream,
                     ps, pbx, ap, gl, gtb, pad, topk, nstar, astar, maxm, maxi);
  hipLaunchKernelGGL(loss_kernel, dim3((NL + 255) / 256, NB), dim3(256), 0, stream,
                     ps, pbx, gtb, gl, nstar, astar, maxm, maxi, acc);
  hipLaunchKernelGGL(fin_kernel, dim3(1), dim3(1), 0, stream, acc, (float*)d_out);
}